// Round 12
// baseline (305.465 us; speedup 1.0000x reference)
//
#include <hip/hip_runtime.h>

typedef __attribute__((ext_vector_type(4))) float floatx4;
typedef __attribute__((ext_vector_type(8))) _Float16 half8;
typedef __attribute__((ext_vector_type(4))) _Float16 half4;

#define TT 2048
#define HIDDEN 2048
#define NH 32
#define NKV 8
#define HD 128
#define QSIZE 4096
#define KVSIZE 1024
#define QKVN 6144
#define WQR 6400     // Wqkvt rows (padded to 256 multiple for 256-tile GEMM)
#define GOFF 6144
#define QKSTR 5120   // QKb row stride (Q 4096 + K 1024)
#define WINDOW 512

// ---- unified prep: w_qkv^T, w_o^T, cvt, pad-zero, w_g^T, cos/sin table ------
__global__ __launch_bounds__(256) void prep_kernel(
    const float* __restrict__ w_qkv, const float* __restrict__ w_o,
    const float* __restrict__ hidden, const float* __restrict__ w_g,
    const int* __restrict__ positions,
    _Float16* __restrict__ Wqkvt, _Float16* __restrict__ Wot,
    _Float16* __restrict__ Xb, float* __restrict__ tbl) {
  __shared__ float tile[64][68];
  int bid = blockIdx.x;
  int tid = threadIdx.x;
  if (bid >= 5120) {
    if (bid < 7168) {
      int i = ((bid - 5120) * 256 + tid) * 8;
      float4 a = *(const float4*)&hidden[i];
      float4 b = *(const float4*)&hidden[i + 4];
      alignas(16) _Float16 o[8] = {(_Float16)a.x, (_Float16)a.y, (_Float16)a.z, (_Float16)a.w,
                                   (_Float16)b.x, (_Float16)b.y, (_Float16)b.z, (_Float16)b.w};
      *(uint4*)&Xb[i] = *(const uint4*)o;
    } else if (bid < 7392) {
      // zero rows GOFF+NH .. WQR-1 (224 rows)
      int i = ((bid - 7168) * 256 + tid) * 8;
      *(uint4*)&Wqkvt[(size_t)(GOFF + NH) * HIDDEN + i] = (uint4){0, 0, 0, 0};
    } else if (bid < 7456) {
      // w_g [2048][32] -> Wqkvt rows GOFF..GOFF+31 (32x32 tile per block)
      int br = (bid - 7392) * 32;
      int c = tid & 31, r0 = tid >> 5;
      __shared__ float gt[32][33];
#pragma unroll
      for (int i = 0; i < 4; ++i) {
        int r = r0 + 8 * i;
        gt[r][c] = w_g[(size_t)(br + r) * NH + c];
      }
      __syncthreads();
#pragma unroll
      for (int i = 0; i < 4; ++i) {
        int r = r0 + 8 * i;
        Wqkvt[(size_t)(GOFF + r) * HIDDEN + br + c] = (_Float16)gt[c][r];
      }
    } else {
      // cos/sin table: tbl[t*128 + j] = cos, tbl[t*128 + 64 + j] = sin
      int idx = (bid - 7456) * 256 + tid;  // 512 blocks x 256 = 131072 = 2048*64
      int t = idx >> 6, j = idx & 63;
      float pos = (float)positions[t];
      float invf = exp2f(-(float)j * (13.287712379549449f / 64.0f));
      float sn, cs;
      sincosf(pos * invf, &sn, &cs);
      tbl[t * 128 + j] = cs;
      tbl[t * 128 + 64 + j] = sn;
    }
    return;
  }
  const float* in;
  _Float16* out;
  int R, C, tilesX, t;
  if (bid < 3072) { in = w_qkv; out = Wqkvt; R = HIDDEN; C = QKVN; tilesX = 96; t = bid; }
  else           { in = w_o;   out = Wot;   R = QSIZE;  C = HIDDEN; tilesX = 32; t = bid - 3072; }
  int bc = (t % tilesX) * 64, br = (t / tilesX) * 64;
  int rr = tid >> 4, l16 = tid & 15;
#pragma unroll
  for (int it = 0; it < 4; ++it) {
    int r = rr + it * 16;
    *(float4*)&tile[r][l16 * 4] = *(const float4*)&in[(size_t)(br + r) * C + bc + l16 * 4];
  }
  __syncthreads();
  int orow = tid >> 2, rr0 = (tid & 3) * 16;
  alignas(16) _Float16 tmp[16];
#pragma unroll
  for (int jj = 0; jj < 16; ++jj) tmp[jj] = (_Float16)tile[rr0 + jj][orow];
  *(uint4*)&out[(size_t)(bc + orow) * R + br + rr0] = *(const uint4*)&tmp[0];
  *(uint4*)&out[(size_t)(bc + orow) * R + br + rr0 + 8] = *(const uint4*)&tmp[8];
}

// ---------------- async 16B global->LDS (wave-uniform LDS base + lane*16) -------
__device__ __forceinline__ void async16(const _Float16* g, _Float16* l) {
  __builtin_amdgcn_global_load_lds((const __attribute__((address_space(1))) void*)g,
                                   (__attribute__((address_space(3))) void*)l, 16, 0, 0);
}

// ====== 256x256 8-wave GEMM (R4 schedule) + light fused epilogue =============
// K-loop identical to the R4-measured-best variant (63.4us measured R10).
// NEW (R12): 1-D launch, 200 blocks, bijective XCD n-chunk decode
// o=(bid&7)*25+(bid>>3) (200%8==0): each XCD owns all 8 m-tiles x ~3 n-tiles,
// its 3.2MB B-slice becomes L2-resident (FETCH 106->49MB, measured R5/R6) --
// shortening the per-tile vmcnt(0) drain, which is the critical path.
//   nt 0-19  Q/K: coalesced f16 store -> QKb (stride 5120)
//   nt 20-23 V:   direct scatter -> Vf (map bench-verified R8)
//   nt 24    gate: cols 0-31 -> Gate[t][h] (bench-verified R8)
#define G256_K 2048

#define STG_A(ob, mh, kt)                                                        \
  async16(As0 + (size_t)(mh) * 64 * G256_K + (kt), &lds[(ob) + ((mh) * 64 + r0A0) * 64]); \
  async16(As1 + (size_t)(mh) * 64 * G256_K + (kt), &lds[(ob) + ((mh) * 64 + r0A1) * 64]);
#define STG_B(ob, nh, kt)                                                        \
  async16(Bs0 + (size_t)(nh) * 32 * G256_K + (kt), &lds[(ob) + 16384 + ((nh) * 32 + r0B0) * 64]); \
  async16(Bs1 + (size_t)(nh) * 32 * G256_K + (kt), &lds[(ob) + 16384 + ((nh) * 32 + r0B1) * 64]);

#define LD_A(DST, mh)                                                            \
  _Pragma("unroll") for (int fm = 0; fm < 4; ++fm)                               \
  _Pragma("unroll") for (int ks = 0; ks < 2; ++ks)                               \
    DST[fm][ks] = *(const half8*)&LA[(wm * 128 + (mh) * 64 + fm * 16 + lr) * 64 + \
                                     (((ks * 4 + quad) ^ l7) * 8)];
#define LD_B(DST, nh)                                                            \
  _Pragma("unroll") for (int fn = 0; fn < 2; ++fn)                               \
  _Pragma("unroll") for (int ks = 0; ks < 2; ++ks)                               \
    DST[fn][ks] = *(const half8*)&LB[(wn * 64 + (nh) * 32 + fn * 16 + lr) * 64 + \
                                     (((ks * 4 + quad) ^ l7) * 8)];
#define MFMAQ(AS, BS, mh, nh)                                                    \
  __builtin_amdgcn_s_setprio(1);                                                 \
  _Pragma("unroll") for (int fm = 0; fm < 4; ++fm)                               \
  _Pragma("unroll") for (int fn = 0; fn < 2; ++fn)                               \
  _Pragma("unroll") for (int ks = 0; ks < 2; ++ks)                               \
    acc[(mh) * 4 + fm][(nh) * 2 + fn] = __builtin_amdgcn_mfma_f32_16x16x32_f16(  \
        AS[fm][ks], BS[fn][ks], acc[(mh) * 4 + fm][(nh) * 2 + fn], 0, 0, 0);     \
  __builtin_amdgcn_s_setprio(0);
#define VMW0 asm volatile("s_waitcnt vmcnt(0)" ::: "memory")
#define BAR __builtin_amdgcn_s_barrier()
#define SB0 __builtin_amdgcn_sched_barrier(0)

__global__ __launch_bounds__(512, 2) void gemm256_kernel(
    const _Float16* __restrict__ A, const _Float16* __restrict__ Bt,
    _Float16* __restrict__ QKb, _Float16* __restrict__ Vf,
    _Float16* __restrict__ Gate) {
  __shared__ _Float16 lds[65536];  // 128 KiB: 2 bufs x (A 256x64 | B 256x64)
  int tid = threadIdx.x;
  int wave = tid >> 6, lane = tid & 63;
  int wm = wave >> 2, wn = wave & 3;
  int lr = lane & 15, quad = lane >> 4, l7 = lane & 7, l3 = lane >> 3;

  // XCD n-chunk decode (bijective; 200 blocks, 25 per XCD)
  int bid = blockIdx.x;
  int o = (bid & 7) * 25 + (bid >> 3);
  int m0 = (o & 7) * 256;
  int nt = o >> 3;
  int n0 = nt * 256;

  // staging geometry: q-th 1KB chunk (q = wave*2+i) -> 8 rows of a panel
  int q0 = wave * 2, q1 = q0 + 1;
  int r0A0 = (q0 >> 3) * 128 + (q0 & 7) * 8;
  int r0A1 = (q1 >> 3) * 128 + (q1 & 7) * 8;
  int r0B0 = (q0 >> 2) * 64 + (q0 & 3) * 8;
  int r0B1 = (q1 >> 2) * 64 + (q1 & 3) * 8;
  int gA8 = (l7 ^ l3) * 8;  // pre-swizzled source chunk (linear LDS dest)

  const _Float16* As0 = A + (size_t)(m0 + r0A0 + l3) * G256_K + gA8;
  const _Float16* As1 = A + (size_t)(m0 + r0A1 + l3) * G256_K + gA8;
  const _Float16* Bs0 = Bt + (size_t)(n0 + r0B0 + l3) * G256_K + gA8;
  const _Float16* Bs1 = Bt + (size_t)(n0 + r0B1 + l3) * G256_K + gA8;

  floatx4 acc[8][4];
#pragma unroll
  for (int i = 0; i < 8; ++i)
#pragma unroll
    for (int j = 0; j < 4; ++j) acc[i][j] = (floatx4){0.f, 0.f, 0.f, 0.f};

  // prologue: tile 0 -> buf0
  STG_A(0, 0, 0);
  STG_A(0, 1, 0);
  STG_B(0, 0, 0);
  STG_B(0, 1, 0);
  VMW0;
  BAR;
  SB0;

  half8 a0f[4][2], a1f[4][2], b0[2][2], b1[2][2];

  for (int t = 0; t < 32; ++t) {
    int bb = (t & 1) << 15;
    int ob = bb ^ 32768;
    int ktn = (t + 1) * 64;
    bool stg = (t < 31);
    const _Float16* LA = &lds[bb];
    const _Float16* LB = &lds[bb + 16384];

    if (stg) {
      STG_A(ob, 0, ktn);
      STG_B(ob, 0, ktn);
      STG_B(ob, 1, ktn);
      STG_A(ob, 1, ktn);
    }

    LD_B(b0, 0);
    LD_A(a0f, 0);
    MFMAQ(a0f, b0, 0, 0);
    LD_B(b1, 1);
    MFMAQ(a0f, b1, 0, 1);
    LD_A(a1f, 1);
    MFMAQ(a1f, b0, 1, 0);
    MFMAQ(a1f, b1, 1, 1);

    if (stg) VMW0;
    BAR;
    SB0;
  }

  // ================= light fused epilogue =================
  if (nt < 20) {
#pragma unroll
    for (int mh = 0; mh < 2; ++mh)
#pragma unroll
      for (int fm = 0; fm < 4; ++fm)
#pragma unroll
        for (int nh = 0; nh < 2; ++nh)
#pragma unroll
          for (int fn = 0; fn < 2; ++fn)
#pragma unroll
            for (int rr = 0; rr < 4; ++rr) {
              int row = m0 + wm * 128 + mh * 64 + fm * 16 + quad * 4 + rr;
              int col = nt * 256 + wn * 64 + nh * 32 + fn * 16 + lr;
              QKb[(size_t)row * QKSTR + col] = (_Float16)acc[mh * 4 + fm][nh * 2 + fn][rr];
            }
  } else if (nt < 24) {
    // V scatter (bench-verified R8)
#pragma unroll
    for (int mh = 0; mh < 2; ++mh)
#pragma unroll
      for (int fm = 0; fm < 4; ++fm)
#pragma unroll
        for (int nh = 0; nh < 2; ++nh)
#pragma unroll
          for (int fn = 0; fn < 2; ++fn)
#pragma unroll
            for (int rq = 0; rq < 4; ++rq) {
              int row = fm * 16 + quad * 4 + rq;
              int t = m0 + wm * 128 + mh * 64 + row;
              int cg = wn * 64 + nh * 32 + fn * 16 + lr;
              int kh = (nt - 20) * 2 + (cg >> 7);
              int d = cg & 127;
              int sv = t & 63;
              _Float16* vb = Vf + ((size_t)kh * 32 + (t >> 6)) * 8192;
              int c = (d >> 4) * 128 + (sv >> 5) * 64 + ((sv >> 3) & 3) * 16 + (d & 15);
              vb[c * 8 + (sv & 7)] = (_Float16)acc[mh * 4 + fm][nh * 2 + fn][rq];
            }
  } else {
    // gate: cols 0-31 only (bench-verified R8)
    if (wn == 0) {
#pragma unroll
      for (int mh = 0; mh < 2; ++mh)
#pragma unroll
        for (int fm = 0; fm < 4; ++fm)
#pragma unroll
          for (int fn = 0; fn < 2; ++fn)
#pragma unroll
            for (int rq = 0; rq < 4; ++rq) {
              int row = fm * 16 + quad * 4 + rq;
              int t = m0 + wm * 128 + mh * 64 + row;
              int col = fn * 16 + lr;
              Gate[(size_t)t * NH + col] = (_Float16)acc[mh * 4 + fm][fn][rq];
            }
    }
  }
}

// ------- K-only RMSNorm + RoPE (wave per row), table trig; K -> Kf direct ----
// Kf scatter map bench-verified R7. Q normrope is fused into attn (lane-local).
__global__ __launch_bounds__(256) void normrope_k_kernel(
    const _Float16* __restrict__ QKb, const float* __restrict__ kw,
    const float* __restrict__ tbl, _Float16* __restrict__ Kf) {
  int wid = blockIdx.x * 4 + (threadIdx.x >> 6);  // [0, TT*NKV)
  int lane = threadIdx.x & 63;
  int t = wid >> 3, hh = wid & 7;
  const _Float16* src = QKb + (size_t)t * QKSTR + QSIZE + hh * HD;
  float x1 = (float)src[lane];
  float x2 = (float)src[lane + 64];
  float ss = x1 * x1 + x2 * x2;
#pragma unroll
  for (int off = 1; off < 64; off <<= 1) ss += __shfl_xor(ss, off);
  float rr = rsqrtf(ss * (1.0f / 128.0f) + 1e-6f);
  float n1 = x1 * rr * kw[lane];
  float n2 = x2 * rr * kw[lane + 64];
  float cs = tbl[(size_t)t * 128 + lane];
  float sn = tbl[(size_t)t * 128 + 64 + lane];
  float r1 = n1 * cs - n2 * sn;
  float r2 = n2 * cs + n1 * sn;
  int st = t >> 6, jt = (t >> 4) & 3, n16 = t & 15;
  _Float16* kb = Kf + (size_t)(hh * 32 + st) * 8192;
  int c = jt * 256 + (lane >> 5) * 64 + ((lane >> 3) & 3) * 16 + n16;
  kb[c * 8 + (lane & 7)] = (_Float16)r1;
  kb[(c + 128) * 8 + (lane & 7)] = (_Float16)r2;
}

// band swizzle: 8 m-tiles x all-n bands for B-tile temporal sharing.
__device__ __forceinline__ void swizzle_mn(int& m0, int& n0) {
  int ntiles = gridDim.y;
  int pid = blockIdx.x + blockIdx.y * gridDim.x;
  int band = pid / (8 * ntiles);
  int wi = pid - band * (8 * ntiles);
  m0 = (band * 8 + (wi & 7)) * 128;
  n0 = (wi >> 3) * 128;
}

// ---- split-K MFMA GEMM (BK=64, XOR swizzle) -> fp32 PARTIALS (no atomics) ----
__global__ __launch_bounds__(256, 2) void gemm_bt_splitk_kernel(
    const _Float16* __restrict__ A, const _Float16* __restrict__ Bt,
    float* __restrict__ Cp, int M, int N, int K, int Ks) {
  __shared__ _Float16 As[128 * 64];
  __shared__ _Float16 Bs[128 * 64];
  int tid = threadIdx.x;
  int wave = tid >> 6, lane = tid & 63;
  int wm = wave >> 1, wn = wave & 1;
  int m0, n0;
  swizzle_mn(m0, n0);
  int kb = blockIdx.z * Ks;
  float* C = Cp + (size_t)blockIdx.z * M * N;
  int lr = lane & 15;
  int quad = lane >> 4;
  floatx4 acc[4][4];
#pragma unroll
  for (int i = 0; i < 4; ++i)
#pragma unroll
    for (int j = 0; j < 4; ++j) acc[i][j] = (floatx4){0.f, 0.f, 0.f, 0.f};

  for (int k0 = kb; k0 < kb + Ks; k0 += 64) {
    __syncthreads();
#pragma unroll
    for (int it = 0; it < 4; ++it) {
      int c = tid + it * 256;
      int row = c >> 3, j = c & 7;
      int jj = j ^ (row & 7);
      _Float16* la = &As[it * 2048 + wave * 512];
      _Float16* lb = &Bs[it * 2048 + wave * 512];
      async16(&A[(size_t)(m0 + row) * K + k0 + jj * 8], la);
      async16(&Bt[(size_t)(n0 + row) * K + k0 + jj * 8], lb);
    }
    __syncthreads();
#pragma unroll
    for (int kc = 0; kc < 2; ++kc) {
      int ch = kc * 4 + quad;
      half8 a[4], b[4];
#pragma unroll
      for (int i = 0; i < 4; ++i) {
        int r = wm * 64 + i * 16 + lr;
        a[i] = *(const half8*)&As[r * 64 + (ch ^ (r & 7)) * 8];
      }
#pragma unroll
      for (int j = 0; j < 4; ++j) {
        int r = wn * 64 + j * 16 + lr;
        b[j] = *(const half8*)&Bs[r * 64 + (ch ^ (r & 7)) * 8];
      }
#pragma unroll
      for (int i = 0; i < 4; ++i)
#pragma unroll
        for (int j = 0; j < 4; ++j)
          acc[i][j] = __builtin_amdgcn_mfma_f32_16x16x32_f16(a[i], b[j], acc[i][j], 0, 0, 0);
    }
  }
  int rq = quad * 4;
#pragma unroll
  for (int i = 0; i < 4; ++i)
#pragma unroll
    for (int j = 0; j < 4; ++j)
#pragma unroll
      for (int r = 0; r < 4; ++r) {
        int row = m0 + wm * 64 + i * 16 + rq + r;
        int col = n0 + wn * 64 + j * 16 + lr;
        C[(size_t)row * N + col] = acc[i][j][r];
      }
}

// ---- out = P0 + P1 (fp32, float4-vectorized, exactly covers 2048*2048) ------
__global__ __launch_bounds__(256) void reduce2_kernel(const float* __restrict__ P,
                                                      float* __restrict__ out) {
  size_t i = ((size_t)blockIdx.x * 256 + threadIdx.x) * 8;
  const float* Q = P + (size_t)TT * HIDDEN;
  float4 a0 = *(const float4*)&P[i];
  float4 a1 = *(const float4*)&P[i + 4];
  float4 b0 = *(const float4*)&Q[i];
  float4 b1 = *(const float4*)&Q[i + 4];
  a0.x += b0.x; a0.y += b0.y; a0.z += b0.z; a0.w += b0.w;
  a1.x += b1.x; a1.y += b1.y; a1.z += b1.z; a1.w += b1.w;
  *(float4*)&out[i] = a0;
  *(float4*)&out[i + 4] = a1;
}

// ---- MFMA sliding-window attention + FUSED Q RMSNorm/RoPE -------------------
// Lane (quad,n16) holds Q row t0+n16, elems d = kc*32+quad*8+j. RoPE pair
// (d, d+64) = (kc, kc+2): lane-local. Row-sum: shfl_xor 16,32 (sums quads).
#define PSTR 68
#define M0 8.0f
__global__ __launch_bounds__(256, 2) void attn_kernel(
    const _Float16* __restrict__ QKb, const float* __restrict__ qw,
    const float* __restrict__ tbl, const _Float16* __restrict__ Kf,
    const _Float16* __restrict__ Vf, const _Float16* __restrict__ Gate,
    _Float16* __restrict__ Og) {
  const float scale = 0.08838834764831845f;  // 128^-0.5
  __shared__ _Float16 Ps[4][16 * PSTR];
  int tid = threadIdx.x;
  int wave = tid >> 6, lane = tid & 63;
  int n16 = lane & 15, quad = lane >> 4;
  int t0 = blockIdx.x * 16;
  int kh = blockIdx.y;
  int h = kh * 4 + wave;
  _Float16* ps = Ps[wave];

  // ---- fused Q RMSNorm + RoPE (prologue, once per block) ----
  half8 qf[4];
  {
    int tq = t0 + n16;
    half8 rq[4];
#pragma unroll
    for (int kc = 0; kc < 4; ++kc)
      rq[kc] = *(const half8*)&QKb[(size_t)tq * QKSTR + h * HD + kc * 32 + quad * 8];
    float x[4][8];
    float ss = 0.f;
#pragma unroll
    for (int kc = 0; kc < 4; ++kc)
#pragma unroll
      for (int j = 0; j < 8; ++j) {
        x[kc][j] = (float)rq[kc][j];
        ss += x[kc][j] * x[kc][j];
      }
    ss += __shfl_xor(ss, 16);
    ss += __shfl_xor(ss, 32);
    float inv = rsqrtf(ss * (1.0f / 128.0f) + 1e-6f);
#pragma unroll
    for (int kc = 0; kc < 2; ++kc) {
      int d0 = kc * 32 + quad * 8;
      const float* tb = &tbl[(size_t)tq * 128 + d0];
      const float* w1 = &qw[d0];
      const float* w2 = &qw[d0 + 64];
#pragma unroll
      for (int j = 0; j < 8; ++j) {
        float cs = tb[j], sn = tb[64 + j];
        float x1 = x[kc][j] * inv * w1[j];
        float x2 = x[kc + 2][j] * inv * w2[j];
        qf[kc][j] = (_Float16)(x1 * cs - x2 * sn);
        qf[kc + 2][j] = (_Float16)(x2 * cs + x1 * sn);
      }
    }
  }

  floatx4 O[8];
  float lp[4];
#pragma unroll
  for (int jd = 0; jd < 8; ++jd) O[jd] = (floatx4){0.f, 0.f, 0.f, 0.f};
#pragma unroll
  for (int r = 0; r < 4; ++r) lp[r] = 0.f;

  int lo = t0 - (WINDOW - 1);
  if (lo < 0) lo = 0;
  int st0 = lo >> 6;
  int st1 = t0 >> 6;

  half8 kfr[4][4];
  {
    const _Float16* kb = Kf + (size_t)(kh * 32 + st0) * 8192;
#pragma unroll
    for (int jt = 0; jt < 4; ++jt)
#pragma unroll
      for (int kc = 0; kc < 4; ++kc)
        kfr[jt][kc] = *(const half8*)&kb[(jt * 4 + kc) * 512 + lane * 8];
  }

  for (int st = st0; st <= st1; ++st) {
    int s0 = st * 64;
    const _Float16* vb = Vf + (size_t)(kh * 32 + st) * 8192;
    floatx4 S[4];
#pragma unroll
    for (int jt = 0; jt < 4; ++jt) S[jt] = (floatx4){0.f, 0.f, 0.f, 0.f};
#pragma unroll
    for (int jt = 0; jt < 4; ++jt)
#pragma unroll
      for (int kc = 0; kc < 4; ++kc)
        S[jt] = __builtin_amdgcn_mfma_f32_16x16x32_f16(qf[kc], kfr[jt][kc], S[jt], 0, 0, 0);
    if (st < st1) {
      const _Float16* kb = Kf + (size_t)(kh * 32 + st + 1) * 8192;
#pragma unroll
      for (int jt = 0; jt < 4; ++jt)
#pragma unroll
        for (int kc = 0; kc < 4; ++kc)
          kfr[jt][kc] = *(const half8*)&kb[(jt * 4 + kc) * 512 + lane * 8];
    }
    bool interior = (t0 >= s0 + 63) && (t0 + 15 - s0 < WINDOW);
    if (interior) {
#pragma unroll
      for (int r = 0; r < 4; ++r) {
        float rs = 0.f;
#pragma unroll
        for (int jt = 0; jt < 4; ++jt) {
          float p = __expf(__builtin_fmaf(S[jt][r], scale, -M0));
          rs += p;
          ps[(quad * 4 + r) * PSTR + jt * 16 + n16] = (_Float16)p;
        }
        lp[r] += rs;
      }
    } else {
#pragma unroll
      for (int r = 0; r < 4; ++r) {
        int tq = t0 + quad * 4 + r;
        float rs = 0.f;
#pragma unroll
        for (int jt = 0; jt < 4; ++jt) {
          int diff = tq - (s0 + jt * 16 + n16);
          bool ok = (diff >= 0) && (diff < WINDOW);
          float p = ok ? __expf(__builtin_fmaf(S[jt][r], scale, -M0)) : 0.f;
          rs += p;
          ps[(quad * 4 + r) * PSTR + jt * 16 + n16] = (_Float16)p;
        }
        lp[r] += rs;
      }
    }
    half8 pf[2];
#pragma unroll
    for (int kc = 0; kc < 2; ++kc) {
      half4 lo4 = *(const half4*)&ps[n16 * PSTR + kc * 32 + quad * 8];
      half4 hi4 = *(const half4*)&ps[n16 * PSTR + kc * 32 + quad * 8 + 4];
      pf[kc] = (half8){lo4[0], lo4[1], lo4[2], lo4[3], hi4[0], hi4[1], hi4[2], hi4[3]};
    }
#pragma unroll
    for (int jd = 0; jd < 8; ++jd) {
#pragma unroll
      for (int kc = 0; kc < 2; ++kc) {
        half8 vfr = *(const half8*)&vb[(jd * 2 + kc) * 512 + lane * 8];
        O[jd] = __builtin_amdgcn_mfma_f32_16x16x32_f16(pf[kc], vfr, O[jd], 0, 0, 0);
      }
    }
  }
#pragma unroll
  for (int r = 0; r < 4; ++r) {
    float l = lp[r];
#pragma unroll
    for (int off = 1; off < 16; off <<= 1) l += __shfl_xor(l, off);
    int t = t0 + quad * 4 + r;
    float gl = (float)Gate[(size_t)t * NH + h];
    float g = (gl > 0.f) ? gl + log1pf(__expf(-gl)) : log1pf(__expf(gl));
    float inv = g / l;
#pragma unroll
    for (int jd = 0; jd < 8; ++jd)
      Og[(size_t)t * QSIZE + h * HD + jd * 16 + n16] = (_Float16)(O[jd][r] * inv);
  }
}

// ---------------- launcher ----------------
extern "C" void kernel_launch(void* const* d_in, const int* in_sizes, int n_in,
                              void* d_out, int out_size, void* d_ws, size_t ws_size,
                              hipStream_t stream) {
  const int* positions = (const int*)d_in[0];
  const float* hidden = (const float*)d_in[1];
  const float* w_qkv = (const float*)d_in[2];
  const float* w_o = (const float*)d_in[3];
  const float* w_g = (const float*)d_in[4];
  const float* q_norm_w = (const float*)d_in[5];
  const float* k_norm_w = (const float*)d_in[6];
  float* out = (float*)d_out;

  char* ws = (char*)d_ws;
  size_t off = 0;
  auto alloc = [&](size_t bytes) {
    void* p = ws + off;
    off += (bytes + 255) & ~(size_t)255;
    return p;
  };
  _Float16* Xb = (_Float16*)alloc((size_t)TT * HIDDEN * 2);
  _Float16* Wqkvt = (_Float16*)alloc((size_t)WQR * HIDDEN * 2);
  _Float16* Wot = (_Float16*)alloc((size_t)HIDDEN * QSIZE * 2);
  _Float16* QKb = (_Float16*)alloc((size_t)TT * QKSTR * 2);
  _Float16* Kf = (_Float16*)alloc((size_t)NKV * 32 * 8192 * 2);
  _Float16* Vf = (_Float16*)alloc((size_t)NKV * 32 * 8192 * 2);
  _Float16* Og = (_Float16*)alloc((size_t)TT * QSIZE * 2);
  _Float16* Gate = (_Float16*)alloc((size_t)TT * NH * 2);
  float* CosSin = (float*)alloc((size_t)TT * 128 * 4);
  // fp32 split-K partials (2 x 16 MiB = 32 MiB) alias the Xb+Wqkvt region
  // (8.4 MB + 26.2 MB = 34.6 MB), dead by the time the O-proj runs.
  float* Cp = (float*)ws;

  prep_kernel<<<7968, 256, 0, stream>>>(w_qkv, w_o, hidden, w_g, positions,
                                        Wqkvt, Wot, Xb, CosSin);
  gemm256_kernel<<<200, 512, 0, stream>>>(Xb, Wqkvt, QKb, Vf, Gate);
  normrope_k_kernel<<<(TT * NKV) / 4, 256, 0, stream>>>(QKb, k_norm_w, CosSin, Kf);
  attn_kernel<<<dim3(TT / 16, NKV), 256, 0, stream>>>(QKb, q_norm_w, CosSin,
                                                      Kf, Vf, Gate, Og);
  gemm_bt_splitk_kernel<<<dim3(TT / 128, HIDDEN / 128, 2), 256, 0, stream>>>(
      Og, Wot, Cp, TT, HIDDEN, QSIZE, QSIZE / 2);
  reduce2_kernel<<<(TT * HIDDEN) / (256 * 8), 256, 0, stream>>>(Cp, out);
}

// Round 13
// 298.546 us; speedup vs baseline: 1.0232x; 1.0232x over previous
//
#include <hip/hip_runtime.h>

typedef __attribute__((ext_vector_type(4))) float floatx4;
typedef __attribute__((ext_vector_type(8))) _Float16 half8;
typedef __attribute__((ext_vector_type(4))) _Float16 half4;

#define TT 2048
#define HIDDEN 2048
#define NH 32
#define NKV 8
#define HD 128
#define QSIZE 4096
#define KVSIZE 1024
#define QKVN 6144
#define WQR 6400     // Wqkvt rows (padded to 256 multiple for 256-tile GEMM)
#define GOFF 6144
#define QKSTR 5120   // QKb row stride (Q 4096 + K 1024)
#define WINDOW 512

// ---- unified prep: w_qkv^T, w_o^T, cvt, pad-zero, w_g^T, cos/sin table ------
__global__ __launch_bounds__(256) void prep_kernel(
    const float* __restrict__ w_qkv, const float* __restrict__ w_o,
    const float* __restrict__ hidden, const float* __restrict__ w_g,
    const int* __restrict__ positions,
    _Float16* __restrict__ Wqkvt, _Float16* __restrict__ Wot,
    _Float16* __restrict__ Xb, float* __restrict__ tbl) {
  __shared__ float tile[64][68];
  int bid = blockIdx.x;
  int tid = threadIdx.x;
  if (bid >= 5120) {
    if (bid < 7168) {
      int i = ((bid - 5120) * 256 + tid) * 8;
      float4 a = *(const float4*)&hidden[i];
      float4 b = *(const float4*)&hidden[i + 4];
      alignas(16) _Float16 o[8] = {(_Float16)a.x, (_Float16)a.y, (_Float16)a.z, (_Float16)a.w,
                                   (_Float16)b.x, (_Float16)b.y, (_Float16)b.z, (_Float16)b.w};
      *(uint4*)&Xb[i] = *(const uint4*)o;
    } else if (bid < 7392) {
      // zero rows GOFF+NH .. WQR-1 (224 rows)
      int i = ((bid - 7168) * 256 + tid) * 8;
      *(uint4*)&Wqkvt[(size_t)(GOFF + NH) * HIDDEN + i] = (uint4){0, 0, 0, 0};
    } else if (bid < 7456) {
      // w_g [2048][32] -> Wqkvt rows GOFF..GOFF+31 (32x32 tile per block)
      int br = (bid - 7392) * 32;
      int c = tid & 31, r0 = tid >> 5;
      __shared__ float gt[32][33];
#pragma unroll
      for (int i = 0; i < 4; ++i) {
        int r = r0 + 8 * i;
        gt[r][c] = w_g[(size_t)(br + r) * NH + c];
      }
      __syncthreads();
#pragma unroll
      for (int i = 0; i < 4; ++i) {
        int r = r0 + 8 * i;
        Wqkvt[(size_t)(GOFF + r) * HIDDEN + br + c] = (_Float16)gt[c][r];
      }
    } else {
      // cos/sin table: tbl[t*128 + j] = cos, tbl[t*128 + 64 + j] = sin
      int idx = (bid - 7456) * 256 + tid;  // 512 blocks x 256 = 131072 = 2048*64
      int t = idx >> 6, j = idx & 63;
      float pos = (float)positions[t];
      float invf = exp2f(-(float)j * (13.287712379549449f / 64.0f));
      float sn, cs;
      sincosf(pos * invf, &sn, &cs);
      tbl[t * 128 + j] = cs;
      tbl[t * 128 + 64 + j] = sn;
    }
    return;
  }
  const float* in;
  _Float16* out;
  int R, C, tilesX, t;
  if (bid < 3072) { in = w_qkv; out = Wqkvt; R = HIDDEN; C = QKVN; tilesX = 96; t = bid; }
  else           { in = w_o;   out = Wot;   R = QSIZE;  C = HIDDEN; tilesX = 32; t = bid - 3072; }
  int bc = (t % tilesX) * 64, br = (t / tilesX) * 64;
  int rr = tid >> 4, l16 = tid & 15;
#pragma unroll
  for (int it = 0; it < 4; ++it) {
    int r = rr + it * 16;
    *(float4*)&tile[r][l16 * 4] = *(const float4*)&in[(size_t)(br + r) * C + bc + l16 * 4];
  }
  __syncthreads();
  int orow = tid >> 2, rr0 = (tid & 3) * 16;
  alignas(16) _Float16 tmp[16];
#pragma unroll
  for (int jj = 0; jj < 16; ++jj) tmp[jj] = (_Float16)tile[rr0 + jj][orow];
  *(uint4*)&out[(size_t)(bc + orow) * R + br + rr0] = *(const uint4*)&tmp[0];
  *(uint4*)&out[(size_t)(bc + orow) * R + br + rr0 + 8] = *(const uint4*)&tmp[8];
}

// ---------------- async 16B global->LDS (wave-uniform LDS base + lane*16) -------
__device__ __forceinline__ void async16(const _Float16* g, _Float16* l) {
  __builtin_amdgcn_global_load_lds((const __attribute__((address_space(1))) void*)g,
                                   (__attribute__((address_space(3))) void*)l, 16, 0, 0);
}

// ====== 256x256 8-wave GEMM (R4 schedule) + light fused epilogue =============
// K-loop identical to the R4-measured-best variant (63.4us measured R10).
//   nt 0-19  Q/K: coalesced f16 store -> QKb (stride 5120)
//   nt 20-23 V:   direct scatter -> Vf (map bench-verified R8)
//   nt 24    gate: cols 0-31 -> Gate[t][h] (bench-verified R8)
#define G256_K 2048

#define STG_A(ob, mh, kt)                                                        \
  async16(As0 + (size_t)(mh) * 64 * G256_K + (kt), &lds[(ob) + ((mh) * 64 + r0A0) * 64]); \
  async16(As1 + (size_t)(mh) * 64 * G256_K + (kt), &lds[(ob) + ((mh) * 64 + r0A1) * 64]);
#define STG_B(ob, nh, kt)                                                        \
  async16(Bs0 + (size_t)(nh) * 32 * G256_K + (kt), &lds[(ob) + 16384 + ((nh) * 32 + r0B0) * 64]); \
  async16(Bs1 + (size_t)(nh) * 32 * G256_K + (kt), &lds[(ob) + 16384 + ((nh) * 32 + r0B1) * 64]);

#define LD_A(DST, mh)                                                            \
  _Pragma("unroll") for (int fm = 0; fm < 4; ++fm)                               \
  _Pragma("unroll") for (int ks = 0; ks < 2; ++ks)                               \
    DST[fm][ks] = *(const half8*)&LA[(wm * 128 + (mh) * 64 + fm * 16 + lr) * 64 + \
                                     (((ks * 4 + quad) ^ l7) * 8)];
#define LD_B(DST, nh)                                                            \
  _Pragma("unroll") for (int fn = 0; fn < 2; ++fn)                               \
  _Pragma("unroll") for (int ks = 0; ks < 2; ++ks)                               \
    DST[fn][ks] = *(const half8*)&LB[(wn * 64 + (nh) * 32 + fn * 16 + lr) * 64 + \
                                     (((ks * 4 + quad) ^ l7) * 8)];
#define MFMAQ(AS, BS, mh, nh)                                                    \
  __builtin_amdgcn_s_setprio(1);                                                 \
  _Pragma("unroll") for (int fm = 0; fm < 4; ++fm)                               \
  _Pragma("unroll") for (int fn = 0; fn < 2; ++fn)                               \
  _Pragma("unroll") for (int ks = 0; ks < 2; ++ks)                               \
    acc[(mh) * 4 + fm][(nh) * 2 + fn] = __builtin_amdgcn_mfma_f32_16x16x32_f16(  \
        AS[fm][ks], BS[fn][ks], acc[(mh) * 4 + fm][(nh) * 2 + fn], 0, 0, 0);     \
  __builtin_amdgcn_s_setprio(0);
#define VMW0 asm volatile("s_waitcnt vmcnt(0)" ::: "memory")
#define BAR __builtin_amdgcn_s_barrier()
#define SB0 __builtin_amdgcn_sched_barrier(0)

__global__ __launch_bounds__(512, 2) void gemm256_kernel(
    const _Float16* __restrict__ A, const _Float16* __restrict__ Bt,
    _Float16* __restrict__ QKb, _Float16* __restrict__ Vf,
    _Float16* __restrict__ Gate) {
  __shared__ _Float16 lds[65536];  // 128 KiB: 2 bufs x (A 256x64 | B 256x64)
  int tid = threadIdx.x;
  int wave = tid >> 6, lane = tid & 63;
  int wm = wave >> 2, wn = wave & 3;
  int lr = lane & 15, quad = lane >> 4, l7 = lane & 7, l3 = lane >> 3;
  int m0 = blockIdx.x * 256, n0 = blockIdx.y * 256;

  // staging geometry: q-th 1KB chunk (q = wave*2+i) -> 8 rows of a panel
  int q0 = wave * 2, q1 = q0 + 1;
  int r0A0 = (q0 >> 3) * 128 + (q0 & 7) * 8;
  int r0A1 = (q1 >> 3) * 128 + (q1 & 7) * 8;
  int r0B0 = (q0 >> 2) * 64 + (q0 & 3) * 8;
  int r0B1 = (q1 >> 2) * 64 + (q1 & 3) * 8;
  int gA8 = (l7 ^ l3) * 8;  // pre-swizzled source chunk (linear LDS dest)

  const _Float16* As0 = A + (size_t)(m0 + r0A0 + l3) * G256_K + gA8;
  const _Float16* As1 = A + (size_t)(m0 + r0A1 + l3) * G256_K + gA8;
  const _Float16* Bs0 = Bt + (size_t)(n0 + r0B0 + l3) * G256_K + gA8;
  const _Float16* Bs1 = Bt + (size_t)(n0 + r0B1 + l3) * G256_K + gA8;

  floatx4 acc[8][4];
#pragma unroll
  for (int i = 0; i < 8; ++i)
#pragma unroll
    for (int j = 0; j < 4; ++j) acc[i][j] = (floatx4){0.f, 0.f, 0.f, 0.f};

  // prologue: tile 0 -> buf0
  STG_A(0, 0, 0);
  STG_A(0, 1, 0);
  STG_B(0, 0, 0);
  STG_B(0, 1, 0);
  VMW0;
  BAR;
  SB0;

  half8 a0f[4][2], a1f[4][2], b0[2][2], b1[2][2];

  for (int t = 0; t < 32; ++t) {
    int bb = (t & 1) << 15;
    int ob = bb ^ 32768;
    int ktn = (t + 1) * 64;
    bool stg = (t < 31);
    const _Float16* LA = &lds[bb];
    const _Float16* LB = &lds[bb + 16384];

    if (stg) {
      STG_A(ob, 0, ktn);
      STG_B(ob, 0, ktn);
      STG_B(ob, 1, ktn);
      STG_A(ob, 1, ktn);
    }

    LD_B(b0, 0);
    LD_A(a0f, 0);
    MFMAQ(a0f, b0, 0, 0);
    LD_B(b1, 1);
    MFMAQ(a0f, b1, 0, 1);
    LD_A(a1f, 1);
    MFMAQ(a1f, b0, 1, 0);
    MFMAQ(a1f, b1, 1, 1);

    if (stg) VMW0;
    BAR;
    SB0;
  }

  // ================= light fused epilogue =================
  int nt = blockIdx.y;   // 0-19 Q/K raw | 20-23 V scatter | 24 gate
  if (nt < 20) {
#pragma unroll
    for (int mh = 0; mh < 2; ++mh)
#pragma unroll
      for (int fm = 0; fm < 4; ++fm)
#pragma unroll
        for (int nh = 0; nh < 2; ++nh)
#pragma unroll
          for (int fn = 0; fn < 2; ++fn)
#pragma unroll
            for (int rr = 0; rr < 4; ++rr) {
              int row = m0 + wm * 128 + mh * 64 + fm * 16 + quad * 4 + rr;
              int col = nt * 256 + wn * 64 + nh * 32 + fn * 16 + lr;
              QKb[(size_t)row * QKSTR + col] = (_Float16)acc[mh * 4 + fm][nh * 2 + fn][rr];
            }
  } else if (nt < 24) {
    // V scatter (bench-verified R8)
#pragma unroll
    for (int mh = 0; mh < 2; ++mh)
#pragma unroll
      for (int fm = 0; fm < 4; ++fm)
#pragma unroll
        for (int nh = 0; nh < 2; ++nh)
#pragma unroll
          for (int fn = 0; fn < 2; ++fn)
#pragma unroll
            for (int rq = 0; rq < 4; ++rq) {
              int row = fm * 16 + quad * 4 + rq;
              int t = m0 + wm * 128 + mh * 64 + row;
              int cg = wn * 64 + nh * 32 + fn * 16 + lr;
              int kh = (nt - 20) * 2 + (cg >> 7);
              int d = cg & 127;
              int sv = t & 63;
              _Float16* vb = Vf + ((size_t)kh * 32 + (t >> 6)) * 8192;
              int c = (d >> 4) * 128 + (sv >> 5) * 64 + ((sv >> 3) & 3) * 16 + (d & 15);
              vb[c * 8 + (sv & 7)] = (_Float16)acc[mh * 4 + fm][nh * 2 + fn][rq];
            }
  } else {
    // gate: cols 0-31 only (bench-verified R8)
    if (wn == 0) {
#pragma unroll
      for (int mh = 0; mh < 2; ++mh)
#pragma unroll
        for (int fm = 0; fm < 4; ++fm)
#pragma unroll
          for (int fn = 0; fn < 2; ++fn)
#pragma unroll
            for (int rq = 0; rq < 4; ++rq) {
              int row = fm * 16 + quad * 4 + rq;
              int t = m0 + wm * 128 + mh * 64 + row;
              int col = fn * 16 + lr;
              Gate[(size_t)t * NH + col] = (_Float16)acc[mh * 4 + fm][fn][rq];
            }
    }
  }
}

// ------- K-only RMSNorm + RoPE (wave per row), table trig; K -> Kf direct ----
// Kf scatter map bench-verified R7. Q normrope is fused into attn (lane-local).
__global__ __launch_bounds__(256) void normrope_k_kernel(
    const _Float16* __restrict__ QKb, const float* __restrict__ kw,
    const float* __restrict__ tbl, _Float16* __restrict__ Kf) {
  int wid = blockIdx.x * 4 + (threadIdx.x >> 6);  // [0, TT*NKV)
  int lane = threadIdx.x & 63;
  int t = wid >> 3, hh = wid & 7;
  const _Float16* src = QKb + (size_t)t * QKSTR + QSIZE + hh * HD;
  float x1 = (float)src[lane];
  float x2 = (float)src[lane + 64];
  float ss = x1 * x1 + x2 * x2;
#pragma unroll
  for (int off = 1; off < 64; off <<= 1) ss += __shfl_xor(ss, off);
  float rr = rsqrtf(ss * (1.0f / 128.0f) + 1e-6f);
  float n1 = x1 * rr * kw[lane];
  float n2 = x2 * rr * kw[lane + 64];
  float cs = tbl[(size_t)t * 128 + lane];
  float sn = tbl[(size_t)t * 128 + 64 + lane];
  float r1 = n1 * cs - n2 * sn;
  float r2 = n2 * cs + n1 * sn;
  int st = t >> 6, jt = (t >> 4) & 3, n16 = t & 15;
  _Float16* kb = Kf + (size_t)(hh * 32 + st) * 8192;
  int c = jt * 256 + (lane >> 5) * 64 + ((lane >> 3) & 3) * 16 + n16;
  kb[c * 8 + (lane & 7)] = (_Float16)r1;
  kb[(c + 128) * 8 + (lane & 7)] = (_Float16)r2;
}

// band swizzle: 8 m-tiles x all-n bands for B-tile temporal sharing.
__device__ __forceinline__ void swizzle_mn(int& m0, int& n0) {
  int ntiles = gridDim.y;
  int pid = blockIdx.x + blockIdx.y * gridDim.x;
  int band = pid / (8 * ntiles);
  int wi = pid - band * (8 * ntiles);
  m0 = (band * 8 + (wi & 7)) * 128;
  n0 = (wi >> 3) * 128;
}

// ---- split-K MFMA GEMM (BK=64, XOR swizzle) -> fp32 PARTIALS (no atomics) ----
__global__ __launch_bounds__(256, 2) void gemm_bt_splitk_kernel(
    const _Float16* __restrict__ A, const _Float16* __restrict__ Bt,
    float* __restrict__ Cp, int M, int N, int K, int Ks) {
  __shared__ _Float16 As[128 * 64];
  __shared__ _Float16 Bs[128 * 64];
  int tid = threadIdx.x;
  int wave = tid >> 6, lane = tid & 63;
  int wm = wave >> 1, wn = wave & 1;
  int m0, n0;
  swizzle_mn(m0, n0);
  int kb = blockIdx.z * Ks;
  float* C = Cp + (size_t)blockIdx.z * M * N;
  int lr = lane & 15;
  int quad = lane >> 4;
  floatx4 acc[4][4];
#pragma unroll
  for (int i = 0; i < 4; ++i)
#pragma unroll
    for (int j = 0; j < 4; ++j) acc[i][j] = (floatx4){0.f, 0.f, 0.f, 0.f};

  for (int k0 = kb; k0 < kb + Ks; k0 += 64) {
    __syncthreads();
#pragma unroll
    for (int it = 0; it < 4; ++it) {
      int c = tid + it * 256;
      int row = c >> 3, j = c & 7;
      int jj = j ^ (row & 7);
      _Float16* la = &As[it * 2048 + wave * 512];
      _Float16* lb = &Bs[it * 2048 + wave * 512];
      async16(&A[(size_t)(m0 + row) * K + k0 + jj * 8], la);
      async16(&Bt[(size_t)(n0 + row) * K + k0 + jj * 8], lb);
    }
    __syncthreads();
#pragma unroll
    for (int kc = 0; kc < 2; ++kc) {
      int ch = kc * 4 + quad;
      half8 a[4], b[4];
#pragma unroll
      for (int i = 0; i < 4; ++i) {
        int r = wm * 64 + i * 16 + lr;
        a[i] = *(const half8*)&As[r * 64 + (ch ^ (r & 7)) * 8];
      }
#pragma unroll
      for (int j = 0; j < 4; ++j) {
        int r = wn * 64 + j * 16 + lr;
        b[j] = *(const half8*)&Bs[r * 64 + (ch ^ (r & 7)) * 8];
      }
#pragma unroll
      for (int i = 0; i < 4; ++i)
#pragma unroll
        for (int j = 0; j < 4; ++j)
          acc[i][j] = __builtin_amdgcn_mfma_f32_16x16x32_f16(a[i], b[j], acc[i][j], 0, 0, 0);
    }
  }
  int rq = quad * 4;
#pragma unroll
  for (int i = 0; i < 4; ++i)
#pragma unroll
    for (int j = 0; j < 4; ++j)
#pragma unroll
      for (int r = 0; r < 4; ++r) {
        int row = m0 + wm * 64 + i * 16 + rq + r;
        int col = n0 + wn * 64 + j * 16 + lr;
        C[(size_t)row * N + col] = acc[i][j][r];
      }
}

// ---- out = P0 + P1 (fp32, float4-vectorized, exactly covers 2048*2048) ------
__global__ __launch_bounds__(256) void reduce2_kernel(const float* __restrict__ P,
                                                      float* __restrict__ out) {
  size_t i = ((size_t)blockIdx.x * 256 + threadIdx.x) * 8;
  const float* Q = P + (size_t)TT * HIDDEN;
  float4 a0 = *(const float4*)&P[i];
  float4 a1 = *(const float4*)&P[i + 4];
  float4 b0 = *(const float4*)&Q[i];
  float4 b1 = *(const float4*)&Q[i + 4];
  a0.x += b0.x; a0.y += b0.y; a0.z += b0.z; a0.w += b0.w;
  a1.x += b1.x; a1.y += b1.y; a1.z += b1.z; a1.w += b1.w;
  *(float4*)&out[i] = a0;
  *(float4*)&out[i + 4] = a1;
}

// ---- MFMA sliding-window attention + FUSED Q RMSNorm/RoPE -------------------
// NEW (R13): K/V tiles staged once per block into LDS (global_load_lds,
// double-buffered, R4-proven stage-ahead + vmcnt(0)+barrier) -- kills the 4x
// redundant per-wave L2 reads (1.2 GB -> 0.3 GB block-aggregate). Fragment
// reads become ds_read_b128 from the contiguous fragment-linear tile.
// Q norm/rope prologue unchanged (lane-local pair; shfl 16,32 row-sum).
#define PSTR 68
#define M0 8.0f
__global__ __launch_bounds__(256, 2) void attn_kernel(
    const _Float16* __restrict__ QKb, const float* __restrict__ qw,
    const float* __restrict__ tbl, const _Float16* __restrict__ Kf,
    const _Float16* __restrict__ Vf, const _Float16* __restrict__ Gate,
    _Float16* __restrict__ Og) {
  const float scale = 0.08838834764831845f;  // 128^-0.5
  __shared__ _Float16 KV[2][16384];  // [K 8192 | V 8192] halves, double-buffered
  __shared__ _Float16 Ps[4][16 * PSTR];
  int tid = threadIdx.x;
  int wave = tid >> 6, lane = tid & 63;
  int n16 = lane & 15, quad = lane >> 4;
  int t0 = blockIdx.x * 16;
  int kh = blockIdx.y;
  int h = kh * 4 + wave;
  _Float16* ps = Ps[wave];

  int lo = t0 - (WINDOW - 1);
  if (lo < 0) lo = 0;
  int st0 = lo >> 6;
  int st1 = t0 >> 6;

  // stage tile st0 into KV[0] (K 16KB + V 16KB; 8 async16 per thread-pass)
  {
    const _Float16* kb = Kf + (size_t)(kh * 32 + st0) * 8192;
    const _Float16* vb = Vf + (size_t)(kh * 32 + st0) * 8192;
#pragma unroll
    for (int it = 0; it < 4; ++it) {
      async16(kb + ((size_t)it * 256 + tid) * 8, &KV[0][it * 2048 + wave * 512]);
      async16(vb + ((size_t)it * 256 + tid) * 8, &KV[0][8192 + it * 2048 + wave * 512]);
    }
  }

  // ---- fused Q RMSNorm + RoPE (overlaps st0 staging) ----
  half8 qf[4];
  {
    int tq = t0 + n16;
    half8 rq[4];
#pragma unroll
    for (int kc = 0; kc < 4; ++kc)
      rq[kc] = *(const half8*)&QKb[(size_t)tq * QKSTR + h * HD + kc * 32 + quad * 8];
    float x[4][8];
    float ss = 0.f;
#pragma unroll
    for (int kc = 0; kc < 4; ++kc)
#pragma unroll
      for (int j = 0; j < 8; ++j) {
        x[kc][j] = (float)rq[kc][j];
        ss += x[kc][j] * x[kc][j];
      }
    ss += __shfl_xor(ss, 16);
    ss += __shfl_xor(ss, 32);
    float inv = rsqrtf(ss * (1.0f / 128.0f) + 1e-6f);
#pragma unroll
    for (int kc = 0; kc < 2; ++kc) {
      int d0 = kc * 32 + quad * 8;
      const float* tb = &tbl[(size_t)tq * 128 + d0];
      const float* w1 = &qw[d0];
      const float* w2 = &qw[d0 + 64];
#pragma unroll
      for (int j = 0; j < 8; ++j) {
        float cs = tb[j], sn = tb[64 + j];
        float x1 = x[kc][j] * inv * w1[j];
        float x2 = x[kc + 2][j] * inv * w2[j];
        qf[kc][j] = (_Float16)(x1 * cs - x2 * sn);
        qf[kc + 2][j] = (_Float16)(x2 * cs + x1 * sn);
      }
    }
  }

  floatx4 O[8];
  float lp[4];
#pragma unroll
  for (int jd = 0; jd < 8; ++jd) O[jd] = (floatx4){0.f, 0.f, 0.f, 0.f};
#pragma unroll
  for (int r = 0; r < 4; ++r) lp[r] = 0.f;

  VMW0;
  BAR;
  SB0;

  for (int st = st0; st <= st1; ++st) {
    int b = (st - st0) & 1;
    const _Float16* Kb = KV[b];
    const _Float16* Vb = KV[b] + 8192;
    bool stg = (st < st1);
    if (stg) {
      const _Float16* kb = Kf + (size_t)(kh * 32 + st + 1) * 8192;
      const _Float16* vb = Vf + (size_t)(kh * 32 + st + 1) * 8192;
      int ob = b ^ 1;
#pragma unroll
      for (int it = 0; it < 4; ++it) {
        async16(kb + ((size_t)it * 256 + tid) * 8, &KV[ob][it * 2048 + wave * 512]);
        async16(vb + ((size_t)it * 256 + tid) * 8, &KV[ob][8192 + it * 2048 + wave * 512]);
      }
    }
    int s0 = st * 64;
    floatx4 S[4];
#pragma unroll
    for (int jt = 0; jt < 4; ++jt) S[jt] = (floatx4){0.f, 0.f, 0.f, 0.f};
#pragma unroll
    for (int jt = 0; jt < 4; ++jt)
#pragma unroll
      for (int kc = 0; kc < 4; ++kc) {
        half8 kfr = *(const half8*)&Kb[(jt * 4 + kc) * 512 + lane * 8];
        S[jt] = __builtin_amdgcn_mfma_f32_16x16x32_f16(qf[kc], kfr, S[jt], 0, 0, 0);
      }
    bool interior = (t0 >= s0 + 63) && (t0 + 15 - s0 < WINDOW);
    if (interior) {
#pragma unroll
      for (int r = 0; r < 4; ++r) {
        float rs = 0.f;
#pragma unroll
        for (int jt = 0; jt < 4; ++jt) {
          float p = __expf(__builtin_fmaf(S[jt][r], scale, -M0));
          rs += p;
          ps[(quad * 4 + r) * PSTR + jt * 16 + n16] = (_Float16)p;
        }
        lp[r] += rs;
      }
    } else {
#pragma unroll
      for (int r = 0; r < 4; ++r) {
        int tq = t0 + quad * 4 + r;
        float rs = 0.f;
#pragma unroll
        for (int jt = 0; jt < 4; ++jt) {
          int diff = tq - (s0 + jt * 16 + n16);
          bool ok = (diff >= 0) && (diff < WINDOW);
          float p = ok ? __expf(__builtin_fmaf(S[jt][r], scale, -M0)) : 0.f;
          rs += p;
          ps[(quad * 4 + r) * PSTR + jt * 16 + n16] = (_Float16)p;
        }
        lp[r] += rs;
      }
    }
    half8 pf[2];
#pragma unroll
    for (int kc = 0; kc < 2; ++kc) {
      half4 lo4 = *(const half4*)&ps[n16 * PSTR + kc * 32 + quad * 8];
      half4 hi4 = *(const half4*)&ps[n16 * PSTR + kc * 32 + quad * 8 + 4];
      pf[kc] = (half8){lo4[0], lo4[1], lo4[2], lo4[3], hi4[0], hi4[1], hi4[2], hi4[3]};
    }
#pragma unroll
    for (int jd = 0; jd < 8; ++jd) {
#pragma unroll
      for (int kc = 0; kc < 2; ++kc) {
        half8 vfr = *(const half8*)&Vb[(jd * 2 + kc) * 512 + lane * 8];
        O[jd] = __builtin_amdgcn_mfma_f32_16x16x32_f16(pf[kc], vfr, O[jd], 0, 0, 0);
      }
    }
    if (stg) VMW0;
    BAR;
    SB0;
  }
#pragma unroll
  for (int r = 0; r < 4; ++r) {
    float l = lp[r];
#pragma unroll
    for (int off = 1; off < 16; off <<= 1) l += __shfl_xor(l, off);
    int t = t0 + quad * 4 + r;
    float gl = (float)Gate[(size_t)t * NH + h];
    float g = (gl > 0.f) ? gl + log1pf(__expf(-gl)) : log1pf(__expf(gl));
    float inv = g / l;
#pragma unroll
    for (int jd = 0; jd < 8; ++jd)
      Og[(size_t)t * QSIZE + h * HD + jd * 16 + n16] = (_Float16)(O[jd][r] * inv);
  }
}

// ---------------- launcher ----------------
extern "C" void kernel_launch(void* const* d_in, const int* in_sizes, int n_in,
                              void* d_out, int out_size, void* d_ws, size_t ws_size,
                              hipStream_t stream) {
  const int* positions = (const int*)d_in[0];
  const float* hidden = (const float*)d_in[1];
  const float* w_qkv = (const float*)d_in[2];
  const float* w_o = (const float*)d_in[3];
  const float* w_g = (const float*)d_in[4];
  const float* q_norm_w = (const float*)d_in[5];
  const float* k_norm_w = (const float*)d_in[6];
  float* out = (float*)d_out;

  char* ws = (char*)d_ws;
  size_t off = 0;
  auto alloc = [&](size_t bytes) {
    void* p = ws + off;
    off += (bytes + 255) & ~(size_t)255;
    return p;
  };
  _Float16* Xb = (_Float16*)alloc((size_t)TT * HIDDEN * 2);
  _Float16* Wqkvt = (_Float16*)alloc((size_t)WQR * HIDDEN * 2);
  _Float16* Wot = (_Float16*)alloc((size_t)HIDDEN * QSIZE * 2);
  _Float16* QKb = (_Float16*)alloc((size_t)TT * QKSTR * 2);
  _Float16* Kf = (_Float16*)alloc((size_t)NKV * 32 * 8192 * 2);
  _Float16* Vf = (_Float16*)alloc((size_t)NKV * 32 * 8192 * 2);
  _Float16* Og = (_Float16*)alloc((size_t)TT * QSIZE * 2);
  _Float16* Gate = (_Float16*)alloc((size_t)TT * NH * 2);
  float* CosSin = (float*)alloc((size_t)TT * 128 * 4);
  // fp32 split-K partials (2 x 16 MiB = 32 MiB) alias the Xb+Wqkvt region
  // (8.4 MB + 26.2 MB = 34.6 MB), dead by the time the O-proj runs.
  float* Cp = (float*)ws;

  prep_kernel<<<7968, 256, 0, stream>>>(w_qkv, w_o, hidden, w_g, positions,
                                        Wqkvt, Wot, Xb, CosSin);
  gemm256_kernel<<<dim3(TT / 256, WQR / 256), 512, 0, stream>>>(
      Xb, Wqkvt, QKb, Vf, Gate);
  normrope_k_kernel<<<(TT * NKV) / 4, 256, 0, stream>>>(QKb, k_norm_w, CosSin, Kf);
  attn_kernel<<<dim3(TT / 16, NKV), 256, 0, stream>>>(QKb, q_norm_w, CosSin,
                                                      Kf, Vf, Gate, Og);
  gemm_bt_splitk_kernel<<<dim3(TT / 128, HIDDEN / 128, 2), 256, 0, stream>>>(
      Og, Wot, Cp, TT, HIDDEN, QSIZE, QSIZE / 2);
  reduce2_kernel<<<(TT * HIDDEN) / (256 * 8), 256, 0, stream>>>(Cp, out);
}